// Round 3
// baseline (170.592 us; speedup 1.0000x reference)
//
#include <hip/hip_runtime.h>

#define N 16384
#define K_ACTIVE 50
#define MAT_BIT (1 << 14)
#define NBINS 256
#define NCOPIES 32
#define RPW 4                    // rows per wave
#define BLOCK 256
#define RPB (RPW * (BLOCK / 64)) // 16 rows per block
#define NBLOCKS (N / RPB)        // 1024

// ws layout:
//   hdr[0] = cnt (combined active-column count), hdr[1] = done counter; pad to 256B
//   y[N] floats
//   ghist[NCOPIES * NBINS] ints
//   list[2N] ints (encoded active columns; bit14 selects w_rec)

// Single block: zero ghist + done, build combined active-column list via
// prefix-scan compaction (deterministic, index-ordered), write count.
__global__ void __launch_bounds__(1024) build_all(const float* __restrict__ x,
                                                  const float* __restrict__ yl,
                                                  int* __restrict__ hdr,
                                                  int* __restrict__ list,
                                                  int* __restrict__ ghist,
                                                  int cap) {
    __shared__ int scan[1024];
    const int tid = threadIdx.x;
    for (int i = tid; i < NCOPIES * NBINS; i += 1024) ghist[i] = 0;
    if (tid == 0) hdr[1] = 0;

    const int base = tid * 16;
    float vx[16], vy[16];
    #pragma unroll
    for (int i = 0; i < 4; ++i) {
        float4 a = *(const float4*)(x + base + i * 4);
        float4 b = *(const float4*)(yl + base + i * 4);
        vx[i*4+0]=a.x; vx[i*4+1]=a.y; vx[i*4+2]=a.z; vx[i*4+3]=a.w;
        vy[i*4+0]=b.x; vy[i*4+1]=b.y; vy[i*4+2]=b.z; vy[i*4+3]=b.w;
    }
    int c = 0;
    #pragma unroll
    for (int i = 0; i < 16; ++i) c += (vx[i] > 0.5f) + (vy[i] > 0.5f);
    scan[tid] = c;
    __syncthreads();
    for (int off = 1; off < 1024; off <<= 1) {
        int v = scan[tid];
        int add = (tid >= off) ? scan[tid - off] : 0;
        __syncthreads();
        scan[tid] = v + add;
        __syncthreads();
    }
    int wr = scan[tid] - c;   // exclusive prefix, index-ordered
    #pragma unroll
    for (int i = 0; i < 16; ++i)
        if (vx[i] > 0.5f) { if (wr < cap) list[wr] = base + i; wr++; }
    #pragma unroll
    for (int i = 0; i < 16; ++i)
        if (vy[i] > 0.5f) { if (wr < cap) list[wr] = (base + i) | MAT_BIT; wr++; }
    if (tid == 1023) hdr[0] = scan[1023];
}

// 1024 blocks x 256 threads. Each wave gathers 4 rows (8 independent scattered
// loads in flight per lane across the first 128 list entries). Per-block LDS
// histogram -> 32 global copies. Last block to finish performs the k-WTA
// finalize (threshold + stable lowest-index tie-break, matching lax.top_k).
__global__ void __launch_bounds__(BLOCK) spmv_fused(const float* __restrict__ w_in,
                                                    const float* __restrict__ w_rec,
                                                    int* __restrict__ hdr,
                                                    const int* __restrict__ list,
                                                    float* __restrict__ y,
                                                    int* __restrict__ ghist,
                                                    float* __restrict__ out,
                                                    int cap) {
    __shared__ int hist[NBINS];
    __shared__ int scn[BLOCK];
    __shared__ int s_t, s_need, s_last;
    const int tid = threadIdx.x;
    hist[tid] = 0;   // BLOCK == NBINS
    const int lane = tid & 63;
    const int wid = tid >> 6;
    const int row0 = blockIdx.x * RPB + wid * RPW;
    const size_t off0 = (size_t)row0 * N;
    int n = hdr[0];
    if (n > cap) n = cap;

    float s0 = 0.f, s1 = 0.f, s2 = 0.f, s3 = 0.f;
    if (lane < n) {
        int enc = list[lane];
        const float* p = ((enc & MAT_BIT) ? w_rec : w_in) + off0 + (enc & (N - 1));
        s0 += p[0]; s1 += p[N]; s2 += p[2 * N]; s3 += p[3 * N];
    }
    if (lane + 64 < n) {
        int enc = list[lane + 64];
        const float* p = ((enc & MAT_BIT) ? w_rec : w_in) + off0 + (enc & (N - 1));
        s0 += p[0]; s1 += p[N]; s2 += p[2 * N]; s3 += p[3 * N];
    }
    for (int e = 128 + lane; e < n; e += 64) {   // rare tail
        int enc = list[e];
        const float* p = ((enc & MAT_BIT) ? w_rec : w_in) + off0 + (enc & (N - 1));
        s0 += p[0]; s1 += p[N]; s2 += p[2 * N]; s3 += p[3 * N];
    }
    #pragma unroll
    for (int off = 32; off >= 1; off >>= 1) {
        s0 += __shfl_xor(s0, off, 64);
        s1 += __shfl_xor(s1, off, 64);
        s2 += __shfl_xor(s2, off, 64);
        s3 += __shfl_xor(s3, off, 64);
    }
    __syncthreads();   // hist zeroing complete
    if (lane == 0) {
        y[row0] = s0; y[row0 + 1] = s1; y[row0 + 2] = s2; y[row0 + 3] = s3;
        int b0 = min(max((int)s0, 0), NBINS - 1);
        int b1 = min(max((int)s1, 0), NBINS - 1);
        int b2 = min(max((int)s2, 0), NBINS - 1);
        int b3 = min(max((int)s3, 0), NBINS - 1);
        atomicAdd(&hist[b0], 1); atomicAdd(&hist[b1], 1);
        atomicAdd(&hist[b2], 1); atomicAdd(&hist[b3], 1);
    }
    __syncthreads();
    {
        int c = hist[tid];
        if (c) atomicAdd(&ghist[(blockIdx.x & (NCOPIES - 1)) * NBINS + tid], c);
    }
    __threadfence();   // device-scope release of y stores + ghist atomics
    if (tid == 0) s_last = (atomicAdd(&hdr[1], 1) == NBLOCKS - 1) ? 1 : 0;
    __syncthreads();
    if (!s_last) return;

    // ---------- last block: finalize (k-WTA) ----------
    __threadfence();   // acquire: see all other blocks' y/ghist
    int sh = 0;
    #pragma unroll
    for (int c = 0; c < NCOPIES; ++c) sh += ghist[c * NBINS + tid];
    __syncthreads();   // hist no longer needed as per-block histogram
    hist[tid] = sh;
    __syncthreads();
    // suffix inclusive scan: hist[b] := sum_{b' >= b} counts
    for (int off = 1; off < NBINS; off <<= 1) {
        int add = (tid + off < NBINS) ? hist[tid + off] : 0;
        __syncthreads();
        hist[tid] += add;
        __syncthreads();
    }
    {
        int cum = hist[tid];
        int cumnext = (tid + 1 < NBINS) ? hist[tid + 1] : 0;
        if (cum >= K_ACTIVE && cumnext < K_ACTIVE) {
            s_t = tid;
            s_need = K_ACTIVE - cumnext;
        }
    }
    __syncthreads();
    const int t = s_t;
    const int need = s_need;

    // per-thread contiguous chunk of 64 rows -> stable index order
    const int base2 = tid * 64;
    int c = 0;
    for (int i = 0; i < 64; i += 4) {
        float4 v = *(const float4*)(y + base2 + i);
        c += ((int)v.x == t) + ((int)v.y == t) + ((int)v.z == t) + ((int)v.w == t);
    }
    scn[tid] = c;
    __syncthreads();
    for (int off = 1; off < BLOCK; off <<= 1) {
        int v = scn[tid];
        int add = (tid >= off) ? scn[tid - off] : 0;
        __syncthreads();
        scn[tid] = v + add;
        __syncthreads();
    }
    int run = scn[tid] - c;   // exclusive prefix over index-ordered chunks
    for (int i = 0; i < 64; i += 4) {
        float4 v = *(const float4*)(y + base2 + i);
        float o[4];
        int   b[4] = {(int)v.x, (int)v.y, (int)v.z, (int)v.w};
        #pragma unroll
        for (int j = 0; j < 4; ++j) {
            float r = 0.f;
            if (b[j] > t) r = 1.f;
            else if (b[j] == t) { if (run < need) r = 1.f; run++; }
            o[j] = r;
        }
        *(float4*)(out + base2 + i) = make_float4(o[0], o[1], o[2], o[3]);
    }
}

extern "C" void kernel_launch(void* const* d_in, const int* in_sizes, int n_in,
                              void* d_out, int out_size, void* d_ws, size_t ws_size,
                              hipStream_t stream) {
    const float* x     = (const float*)d_in[0];
    const float* ylat  = (const float*)d_in[1];
    const float* w_in  = (const float*)d_in[2];
    const float* w_rec = (const float*)d_in[3];
    float* out = (float*)d_out;

    char* ws = (char*)d_ws;
    int*   hdr   = (int*)ws;
    float* y     = (float*)(ws + 256);
    int*   ghist = (int*)(ws + 256 + (size_t)N * sizeof(float));
    int*   list  = (int*)(ws + 256 + (size_t)N * sizeof(float)
                          + (size_t)NCOPIES * NBINS * sizeof(int));
    size_t used = 256 + (size_t)N * sizeof(float) + (size_t)NCOPIES * NBINS * sizeof(int);
    long long cap_ll = (ws_size > used) ? (long long)((ws_size - used) / sizeof(int)) : 0;
    int cap = (cap_ll > 2LL * N) ? 2 * N : (int)cap_ll;

    build_all<<<1, 1024, 0, stream>>>(x, ylat, hdr, list, ghist, cap);
    spmv_fused<<<NBLOCKS, BLOCK, 0, stream>>>(w_in, w_rec, hdr, list, y, ghist, out, cap);
}

// Round 4
// 50.458 us; speedup vs baseline: 3.3808x; 3.3808x over previous
//
#include <hip/hip_runtime.h>

#define N 16384
#define K_ACTIVE 50
#define MAT_BIT (1 << 14)
#define NBINS 256
#define NCOPIES 32

// ws layout:
//   [0, 256)    : int hdr (hdr[0] = clamped active-column count)
//   [256, +64K) : float y[N]
//   [+32K)      : int ghist[NCOPIES][NBINS]
//   [+128K)     : int list[2N] (bit14 selects w_rec)

// Single block. Zero ghist; append active columns via LDS-atomic (order
// arbitrary -- provably output-invariant: y is an exact order-independent
// sum of 1.0f, and all later stages depend only on y). No barriers/scans.
__global__ void __launch_bounds__(1024) build_all(const float* __restrict__ x,
                                                  const float* __restrict__ yl,
                                                  int* __restrict__ hdr,
                                                  int* __restrict__ list,
                                                  int* __restrict__ ghist,
                                                  int cap) {
    __shared__ int lcnt;
    const int tid = threadIdx.x;
    if (tid == 0) lcnt = 0;
    for (int i = tid; i < NCOPIES * NBINS; i += 1024) ghist[i] = 0;
    __syncthreads();

    const int base = tid * 16;
    #pragma unroll
    for (int i = 0; i < 4; ++i) {
        float4 a = *(const float4*)(x + base + i * 4);
        float4 b = *(const float4*)(yl + base + i * 4);
        float av[4] = {a.x, a.y, a.z, a.w};
        float bv[4] = {b.x, b.y, b.z, b.w};
        #pragma unroll
        for (int j = 0; j < 4; ++j) {
            if (av[j] > 0.5f) {
                int s = atomicAdd(&lcnt, 1);
                if (s < cap) list[s] = base + i * 4 + j;
            }
            if (bv[j] > 0.5f) {
                int s = atomicAdd(&lcnt, 1);
                if (s < cap) list[s] = (base + i * 4 + j) | MAT_BIT;
            }
        }
    }
    __syncthreads();
    if (tid == 0) hdr[0] = (lcnt < cap) ? lcnt : cap;
}

// 2048 blocks x 256 threads (exactly 32 waves/CU). Each wave gathers 2 rows:
// 4 independent scattered loads in flight per lane. Per-block LDS histogram
// (8 values/block -> no contention), scattered into 32 global copies.
// [R2-measured-good; R3's fused variant regressed 2.5x -- device-scope
//  fences per block are L2 writeback/invalidate class ops on multi-XCD CDNA.]
__global__ void __launch_bounds__(256) spmv_hist(const float* __restrict__ w_in,
                                                 const float* __restrict__ w_rec,
                                                 const int* __restrict__ hdr,
                                                 const int* __restrict__ list,
                                                 float* __restrict__ y,
                                                 int* __restrict__ ghist) {
    __shared__ int hist[NBINS];
    const int tid = threadIdx.x;
    if (tid < NBINS) hist[tid] = 0;
    const int lane = tid & 63;
    const int wid = tid >> 6;
    const int row0 = blockIdx.x * 8 + wid * 2;
    const size_t off0 = (size_t)row0 * N;
    const int n = hdr[0];

    float s0 = 0.f, s1 = 0.f;
    if (lane < n) {
        int enc = list[lane];
        const float* b = (enc & MAT_BIT) ? w_rec : w_in;
        size_t a = off0 + (size_t)(enc & (N - 1));
        s0 += b[a];
        s1 += b[a + N];
    }
    if (lane + 64 < n) {
        int enc = list[lane + 64];
        const float* b = (enc & MAT_BIT) ? w_rec : w_in;
        size_t a = off0 + (size_t)(enc & (N - 1));
        s0 += b[a];
        s1 += b[a + N];
    }
    for (int e = 128 + lane; e < n; e += 64) {   // rare tail
        int enc = list[e];
        const float* b = (enc & MAT_BIT) ? w_rec : w_in;
        size_t a = off0 + (size_t)(enc & (N - 1));
        s0 += b[a];
        s1 += b[a + N];
    }
    #pragma unroll
    for (int off = 32; off >= 1; off >>= 1) {
        s0 += __shfl_xor(s0, off, 64);
        s1 += __shfl_xor(s1, off, 64);
    }
    __syncthreads();   // hist zeroing complete
    if (lane == 0) {
        y[row0] = s0;
        y[row0 + 1] = s1;
        int b0 = min(max((int)s0, 0), NBINS - 1);
        int b1 = min(max((int)s1, 0), NBINS - 1);
        atomicAdd(&hist[b0], 1);
        atomicAdd(&hist[b1], 1);
    }
    __syncthreads();
    if (tid < NBINS) {
        int c = hist[tid];
        if (c) atomicAdd(&ghist[(blockIdx.x & (NCOPIES - 1)) * NBINS + tid], c);
    }
}

// Single block, 1024 threads. Sum hist copies; 256-wide suffix scan for the
// threshold; wave-shuffle scan (3 barriers) for the stable lowest-index-first
// tie-break, matching jax.lax.top_k.
__global__ void __launch_bounds__(1024) finalize(const float* __restrict__ y,
                                                 const int* __restrict__ ghist,
                                                 float* __restrict__ out) {
    __shared__ int shist[NBINS];
    __shared__ int wsum[16];
    __shared__ int s_t, s_need;
    const int tid = threadIdx.x;
    const int lane = tid & 63;
    const int wid = tid >> 6;

    if (tid < NBINS) {
        int s = 0;
        #pragma unroll
        for (int c = 0; c < NCOPIES; ++c) s += ghist[c * NBINS + tid];
        shist[tid] = s;
    }
    __syncthreads();
    // suffix inclusive scan over 256 bins (threads 0..255)
    for (int off = 1; off < NBINS; off <<= 1) {
        int add = 0;
        if (tid < NBINS) add = (tid + off < NBINS) ? shist[tid + off] : 0;
        __syncthreads();
        if (tid < NBINS) shist[tid] += add;
        __syncthreads();
    }
    if (tid < NBINS) {
        int cum = shist[tid];
        int cumnext = (tid + 1 < NBINS) ? shist[tid + 1] : 0;
        if (cum >= K_ACTIVE && cumnext < K_ACTIVE) {
            s_t = tid;
            s_need = K_ACTIVE - cumnext;
        }
    }
    __syncthreads();
    const int t = s_t, need = s_need;

    // per-thread contiguous chunk of 16 rows -> stable index order
    const int base = tid * 16;
    int bins[16];
    int c = 0;
    #pragma unroll
    for (int i = 0; i < 4; ++i) {
        float4 v = *(const float4*)(y + base + i * 4);
        int b0 = min((int)v.x, NBINS - 1), b1 = min((int)v.y, NBINS - 1);
        int b2 = min((int)v.z, NBINS - 1), b3 = min((int)v.w, NBINS - 1);
        bins[i*4+0]=b0; bins[i*4+1]=b1; bins[i*4+2]=b2; bins[i*4+3]=b3;
        c += (b0 == t) + (b1 == t) + (b2 == t) + (b3 == t);
    }
    // wave-level inclusive scan of c
    int inc = c;
    #pragma unroll
    for (int off = 1; off < 64; off <<= 1) {
        int v = __shfl_up(inc, off, 64);
        if (lane >= off) inc += v;
    }
    if (lane == 63) wsum[wid] = inc;
    __syncthreads();
    if (wid == 0 && lane < 16) {
        int v = wsum[lane];
        int s = v;
        #pragma unroll
        for (int off = 1; off < 16; off <<= 1) {
            int u = __shfl_up(s, off, 64);
            if (lane >= off) s += u;
        }
        wsum[lane] = s - v;  // exclusive prefix of wave sums
    }
    __syncthreads();
    int run = wsum[wid] + inc - c;  // exclusive prefix over index-ordered chunks

    #pragma unroll
    for (int i = 0; i < 4; ++i) {
        float o[4];
        #pragma unroll
        for (int j = 0; j < 4; ++j) {
            int b = bins[i * 4 + j];
            float r = 0.f;
            if (b > t) r = 1.f;
            else if (b == t) { if (run < need) r = 1.f; run++; }
            o[j] = r;
        }
        *(float4*)(out + base + i * 4) = make_float4(o[0], o[1], o[2], o[3]);
    }
}

extern "C" void kernel_launch(void* const* d_in, const int* in_sizes, int n_in,
                              void* d_out, int out_size, void* d_ws, size_t ws_size,
                              hipStream_t stream) {
    const float* x     = (const float*)d_in[0];
    const float* ylat  = (const float*)d_in[1];
    const float* w_in  = (const float*)d_in[2];
    const float* w_rec = (const float*)d_in[3];
    float* out = (float*)d_out;

    char* ws = (char*)d_ws;
    int*   hdr   = (int*)ws;
    float* y     = (float*)(ws + 256);
    int*   ghist = (int*)(ws + 256 + (size_t)N * sizeof(float));
    int*   list  = (int*)(ws + 256 + (size_t)N * sizeof(float)
                          + (size_t)NCOPIES * NBINS * sizeof(int));
    size_t used = 256 + (size_t)N * sizeof(float) + (size_t)NCOPIES * NBINS * sizeof(int);
    long long cap_ll = (ws_size > used) ? (long long)((ws_size - used) / sizeof(int)) : 0;
    int cap = (cap_ll > 2LL * N) ? 2 * N : (int)cap_ll;

    build_all<<<1, 1024, 0, stream>>>(x, ylat, hdr, list, ghist, cap);
    spmv_hist<<<N / 8, 256, 0, stream>>>(w_in, w_rec, hdr, list, y, ghist);
    finalize<<<1, 1024, 0, stream>>>(y, ghist, out);
}